// Round 3
// baseline (37287.119 us; speedup 1.0000x reference)
//
#include <hip/hip_runtime.h>
#include <math.h>

#define B 256
#define H 512
#define T 256
#define V 28
#define G4 2048  // 4*H

#define OUT_MU 1835008            // T*B*V
#define OUT_LV (1835008+131072)

__device__ __forceinline__ float fast_sigmoid(float x) {
    x = fminf(fmaxf(x, -30.f), 30.f);
    return 1.0f / (1.0f + __expf(-x));
}
__device__ __forceinline__ float fast_tanh(float x) {
    x = fminf(fmaxf(x, -15.f), 15.f);
    float e = __expf(2.0f * x);
    return (e - 1.0f) / (e + 1.0f);
}

// ---------------------------------------------------------------------------
// Per-rowgroup barrier: 64 blocks sharing rg. Monotonic generation counter.
// Release: each thread fences its own global writes (agent scope), then one
// lane bumps the counter. Acquire: spin on counter, then agent fence so
// subsequent plain loads see remote XCDs' data.
// ---------------------------------------------------------------------------
__device__ __forceinline__ void rg_barrier(int* ctr, int gen) {
    __threadfence();
    __syncthreads();
    if (threadIdx.x == 0) {
        __hip_atomic_fetch_add(ctr, 1, __ATOMIC_RELEASE, __HIP_MEMORY_SCOPE_AGENT);
        while (__hip_atomic_load(ctr, __ATOMIC_ACQUIRE, __HIP_MEMORY_SCOPE_AGENT) < gen * 64) {
            __builtin_amdgcn_s_sleep(1);
        }
    }
    __syncthreads();
    __threadfence();
}

// ---------------------------------------------------------------------------
// K1: proj = embed @ Wi + b (enc mat0 / dec mat1), [28,512]@[512,2048].
// Also zeroes the 4 barrier counters (ws is poisoned 0xAA every replay).
// ---------------------------------------------------------------------------
__global__ __launch_bounds__(256) void proj_kernel(
    const float* __restrict__ enc_embed, const float* __restrict__ enc_Wi, const float* __restrict__ enc_b,
    const float* __restrict__ dec_embed, const float* __restrict__ dec_Wi, const float* __restrict__ dec_b,
    float* __restrict__ enc_proj, float* __restrict__ dec_proj, int* bar)
{
    if (blockIdx.x == 0 && threadIdx.x < 128) bar[threadIdx.x] = 0;
    __shared__ float emb[V][513];
    int mat = blockIdx.x >> 5;
    int cg  = blockIdx.x & 31;
    int c0  = cg * 64;
    const float* embed = mat ? dec_embed : enc_embed;
    const float* Wi    = mat ? dec_Wi    : enc_Wi;
    const float* bias  = mat ? dec_b     : enc_b;
    float*       proj  = mat ? dec_proj  : enc_proj;
    int tid = threadIdx.x;
    #pragma unroll
    for (int i = 0; i < 14; ++i) {
        int u = tid + i * 256;
        int r = u >> 7, q = u & 127;
        float4 vv = *(const float4*)&embed[r * H + q * 4];
        emb[r][q*4+0] = vv.x; emb[r][q*4+1] = vv.y; emb[r][q*4+2] = vv.z; emb[r][q*4+3] = vv.w;
    }
    __syncthreads();
    int col = c0 + (tid & 63);
    int rg  = tid >> 6;
    float acc[7] = {0,0,0,0,0,0,0};
    for (int k = 0; k < H; ++k) {
        float w = Wi[k * G4 + col];
        #pragma unroll
        for (int r = 0; r < 7; ++r) acc[r] += w * emb[rg*7 + r][k];
    }
    float bb = bias[col];
    #pragma unroll
    for (int r = 0; r < 7; ++r) proj[(rg*7 + r) * G4 + col] = acc[r] + bb;
}

// ---------------------------------------------------------------------------
// One LSTM step, executed by a persistent block owning (rg: 64 rows, cg: 8
// h-cols / 32 g-cols). Wh slice persistent in WsL. h tile double-buffered in
// LDS with register prefetch (1 sync/chunk). ZM: h_in/c_in = z recomputed
// from mu/lv/eps. logit_t>=0: fused log-softmax of h_in row (r0+cg).
// ---------------------------------------------------------------------------
#define HT(b, kk, r) htf[(b)*(64*66) + (kk)*66 + (r)]

template<bool ZM>
__device__ __forceinline__ void lstm_step_body(
    int tid, int r0, int hc0, int cg,
    const float* __restrict__ h_in, const float* __restrict__ c_in,
    float* __restrict__ h_out, float* __restrict__ c_out,
    const float* __restrict__ proj, const int* __restrict__ tokv,
    const float* __restrict__ mu_p, const float* __restrict__ lv_p,
    const float* __restrict__ eps_p,
    const float* __restrict__ Wout, const float* __restrict__ bout,
    float* __restrict__ out, int logit_t,
    const float* __restrict__ WsL, float* __restrict__ htf,
    float* __restrict__ gsf, float* __restrict__ lp)
{
    int tx = tid & 7, ty = tid >> 3;

    // fused logit partials for h_in row (r0+cg): strips of 64 k per half-wave
    if (logit_t >= 0) {
        int v = tid & 31, ks = tid >> 5;
        float lacc = 0.f;
        if (v < V) {
            const float* hr = h_in + (r0 + cg) * H + ks * 64;
            const float* wr = Wout + (ks * 64) * V + v;
            #pragma unroll 8
            for (int k = 0; k < 64; ++k) lacc += hr[k] * wr[k * V];
        }
        lp[tid] = lacc;
    }

    float acc0[4] = {0,0,0,0}, acc1[4] = {0,0,0,0};
    float4 pf[4];

    // prefetch chunk 0 into regs
    #pragma unroll
    for (int i = 0; i < 4; ++i) {
        int u = tid + i * 256; int rrow = u >> 4, kq = u & 15;
        int gr = r0 + rrow, kk = kq * 4;
        if (ZM) {
            float4 m4 = *(const float4*)&mu_p[gr*H + kk];
            float4 l4 = *(const float4*)&lv_p[gr*H + kk];
            float4 e4 = *(const float4*)&eps_p[gr*H + kk];
            pf[i].x = m4.x + e4.x * __expf(0.5f*l4.x);
            pf[i].y = m4.y + e4.y * __expf(0.5f*l4.y);
            pf[i].z = m4.z + e4.z * __expf(0.5f*l4.z);
            pf[i].w = m4.w + e4.w * __expf(0.5f*l4.w);
        } else {
            pf[i] = *(const float4*)&h_in[gr*H + kk];
        }
    }
    // store chunk 0 to buf 0 (safe: rg_barrier ended the previous step block-wide)
    #pragma unroll
    for (int i = 0; i < 4; ++i) {
        int u = tid + i * 256; int rrow = u >> 4, kq = u & 15;
        HT(0, kq*4+0, rrow) = pf[i].x; HT(0, kq*4+1, rrow) = pf[i].y;
        HT(0, kq*4+2, rrow) = pf[i].z; HT(0, kq*4+3, rrow) = pf[i].w;
    }
    __syncthreads();

    #pragma unroll 1
    for (int c = 0; c < 8; ++c) {
        if (c < 7) {  // prefetch next chunk (overlaps compute below)
            int kb = (c + 1) * 64;
            #pragma unroll
            for (int i = 0; i < 4; ++i) {
                int u = tid + i * 256; int rrow = u >> 4, kq = u & 15;
                int gr = r0 + rrow, kk = kb + kq * 4;
                if (ZM) {
                    float4 m4 = *(const float4*)&mu_p[gr*H + kk];
                    float4 l4 = *(const float4*)&lv_p[gr*H + kk];
                    float4 e4 = *(const float4*)&eps_p[gr*H + kk];
                    pf[i].x = m4.x + e4.x * __expf(0.5f*l4.x);
                    pf[i].y = m4.y + e4.y * __expf(0.5f*l4.y);
                    pf[i].z = m4.z + e4.z * __expf(0.5f*l4.z);
                    pf[i].w = m4.w + e4.w * __expf(0.5f*l4.w);
                } else {
                    pf[i] = *(const float4*)&h_in[gr*H + kk];
                }
            }
        }
        // compute chunk c from buf (c&1); Ws rows c*64..c*64+63 (persistent LDS)
        const float* wrow = &WsL[c * 64 * 32];
        const float* hbuf = &htf[(c & 1) * (64*66)];
        #pragma unroll
        for (int kk = 0; kk < 64; ++kk) {
            float4 b4 = *(const float4*)&wrow[kk*32 + tx*4];
            float2 a2 = *(const float2*)&hbuf[kk*66 + ty*2];
            acc0[0] += a2.x*b4.x; acc0[1] += a2.x*b4.y; acc0[2] += a2.x*b4.z; acc0[3] += a2.x*b4.w;
            acc1[0] += a2.y*b4.x; acc1[1] += a2.y*b4.y; acc1[2] += a2.y*b4.z; acc1[3] += a2.y*b4.w;
        }
        if (c < 7) {  // store prefetched chunk to the other buffer
            #pragma unroll
            for (int i = 0; i < 4; ++i) {
                int u = tid + i * 256; int rrow = u >> 4, kq = u & 15;
                int b = (c + 1) & 1;
                HT(b, kq*4+0, rrow) = pf[i].x; HT(b, kq*4+1, rrow) = pf[i].y;
                HT(b, kq*4+2, rrow) = pf[i].z; HT(b, kq*4+3, rrow) = pf[i].w;
            }
            __syncthreads();
        }
    }

    // publish g tile
    *(float4*)&gsf[(ty*2+0)*36 + tx*4] = make_float4(acc0[0],acc0[1],acc0[2],acc0[3]);
    *(float4*)&gsf[(ty*2+1)*36 + tx*4] = make_float4(acc1[0],acc1[1],acc1[2],acc1[3]);
    __syncthreads();

    if (tid >= 128) {
        // gates epilogue: waves 2-3, float4, 4 outputs/thread
        int p   = tid - 128;
        int row = p >> 1, q = p & 1;
        int gr  = r0 + row;
        int j   = hc0 + q * 4;
        int tok = tokv ? tokv[gr] : 0;
        const float* pr = proj + tok * G4;
        float4 xi = *(const float4*)&gsf[row*36 +      q*4];
        float4 xf = *(const float4*)&gsf[row*36 +  8 + q*4];
        float4 xg = *(const float4*)&gsf[row*36 + 16 + q*4];
        float4 xo = *(const float4*)&gsf[row*36 + 24 + q*4];
        float4 pi = *(const float4*)&pr[j];
        float4 pv = *(const float4*)&pr[512 + j];
        float4 pg = *(const float4*)&pr[1024 + j];
        float4 po = *(const float4*)&pr[1536 + j];
        float4 cv;
        if (ZM) {
            float4 m4 = *(const float4*)&mu_p[gr*H + j];
            float4 l4 = *(const float4*)&lv_p[gr*H + j];
            float4 e4 = *(const float4*)&eps_p[gr*H + j];
            cv.x = m4.x + e4.x*__expf(0.5f*l4.x);
            cv.y = m4.y + e4.y*__expf(0.5f*l4.y);
            cv.z = m4.z + e4.z*__expf(0.5f*l4.z);
            cv.w = m4.w + e4.w*__expf(0.5f*l4.w);
        } else {
            cv = *(const float4*)&c_in[gr*H + j];
        }
        float4 cn, hn;
        cn.x = fast_sigmoid(xf.x+pv.x)*cv.x + fast_sigmoid(xi.x+pi.x)*fast_tanh(xg.x+pg.x);
        cn.y = fast_sigmoid(xf.y+pv.y)*cv.y + fast_sigmoid(xi.y+pi.y)*fast_tanh(xg.y+pg.y);
        cn.z = fast_sigmoid(xf.z+pv.z)*cv.z + fast_sigmoid(xi.z+pi.z)*fast_tanh(xg.z+pg.z);
        cn.w = fast_sigmoid(xf.w+pv.w)*cv.w + fast_sigmoid(xi.w+pi.w)*fast_tanh(xg.w+pg.w);
        hn.x = fast_sigmoid(xo.x+po.x)*fast_tanh(cn.x);
        hn.y = fast_sigmoid(xo.y+po.y)*fast_tanh(cn.y);
        hn.z = fast_sigmoid(xo.z+po.z)*fast_tanh(cn.z);
        hn.w = fast_sigmoid(xo.w+po.w)*fast_tanh(cn.w);
        *(float4*)&c_out[gr*H + j] = cn;
        *(float4*)&h_out[gr*H + j] = hn;
    } else if (tid < 32 && logit_t >= 0) {
        // fused logit finish: lanes 0-31 of wave 0
        int v = tid;
        float sum = 0.f;
        #pragma unroll
        for (int ks = 0; ks < 8; ++ks) sum += lp[ks * 32 + v];
        float val = (v < V) ? sum + bout[v] : -INFINITY;
        float m = val;
        #pragma unroll
        for (int s = 16; s >= 1; s >>= 1) m = fmaxf(m, __shfl_xor(m, s, 32));
        float e = (v < V) ? __expf(val - m) : 0.f;
        #pragma unroll
        for (int s = 16; s >= 1; s >>= 1) e += __shfl_xor(e, s, 32);
        float lse = m + __logf(e);
        if (v < V) out[(logit_t * B + (r0 + cg)) * V + v] = val - lse;
    }
}

// ---------------------------------------------------------------------------
// Persistent mega-kernel: encoder(256) -> latent -> decoder(256) + logits.
// 256 blocks (1/CU), per-rowgroup barriers between steps.
// LDS: WsL 64K + Ht dbuf 33K + Gs 9K + lp 1K = 107 KB -> 1 block/CU.
// ---------------------------------------------------------------------------
__global__ __launch_bounds__(256, 1) void vae_mega_kernel(
    const int* __restrict__ x, const int* __restrict__ target,
    const float* __restrict__ hidden, const float* __restrict__ eps,
    const float* __restrict__ enc_Wh, const float* __restrict__ dec_Wh,
    const float* __restrict__ Wmu, const float* __restrict__ bmu,
    const float* __restrict__ Wlv, const float* __restrict__ blv,
    const float* __restrict__ Wout, const float* __restrict__ bout,
    const float* __restrict__ enc_proj, const float* __restrict__ dec_proj,
    float* __restrict__ hA, float* __restrict__ hB, float* __restrict__ cbuf,
    int* bar, float* __restrict__ out)
{
    __shared__ float WsL[512 * 32];   // persistent Wh slice
    __shared__ float htf[2 * 64 * 66];
    __shared__ float gsf[64 * 36];
    __shared__ float lp[256];

    int tid = threadIdx.x, bid = blockIdx.x;
    int cg = ((bid & 7) << 3) | ((bid >> 3) & 7);   // XCD-contiguous col bands
    int rg = bid >> 6;
    int r0 = rg << 6, hc0 = cg << 3;
    int gen = 0;
    int* mybar = bar + rg * 32;

    // load encoder Wh slice (visibility covered by step's first __syncthreads)
    #pragma unroll
    for (int i = 0; i < 16; ++i) {
        int u = tid + i * 256;
        int k = u >> 3, f4 = u & 7;
        int gate = f4 >> 1, cc4 = (f4 & 1) * 4;
        *(float4*)&WsL[k*32 + f4*4] = *(const float4*)&enc_Wh[k*G4 + gate*512 + hc0 + cc4];
    }
    float* hb0 = hA; float* hb1 = hB;

    // ---- encoder ----
    #pragma unroll 1
    for (int t = 0; t < T; ++t) {
        const float* hi = (t == 0) ? hidden : ((t & 1) ? hb1 : hb0);
        const float* ci = (t == 0) ? hidden : cbuf;
        float* ho = ((t + 1) & 1) ? hb1 : hb0;
        lstm_step_body<false>(tid, r0, hc0, cg, hi, ci, ho, cbuf,
                              enc_proj, x + t * B, nullptr, nullptr, nullptr,
                              nullptr, nullptr, nullptr, -1, WsL, htf, gsf, lp);
        rg_barrier(mybar, ++gen);
    }

    // ---- latent: mu/logvar from h_enc (= hA) ----
    {
        int mat = cg >> 5;
        int c0  = (cg & 31) * 16;
        const float* W    = mat ? Wlv : Wmu;
        const float* bias = mat ? blv : bmu;
        float* op = out + (mat ? OUT_LV : OUT_MU);
        int j  = c0 + (tid & 15);
        int rq = tid >> 4;
        float acc[4] = {0,0,0,0};
        #pragma unroll 1
        for (int c = 0; c < 8; ++c) {
            __syncthreads();
            #pragma unroll
            for (int i = 0; i < 4; ++i) {
                int u = tid + i * 256; int rrow = u >> 4, kq = u & 15;
                float4 vv = *(const float4*)&hA[(r0 + rrow) * H + c * 64 + kq * 4];
                HT(0, kq*4+0, rrow) = vv.x; HT(0, kq*4+1, rrow) = vv.y;
                HT(0, kq*4+2, rrow) = vv.z; HT(0, kq*4+3, rrow) = vv.w;
            }
            __syncthreads();
            #pragma unroll 8
            for (int kk = 0; kk < 64; ++kk) {
                float w = W[(c*64 + kk) * H + j];
                #pragma unroll
                for (int m = 0; m < 4; ++m) acc[m] += w * HT(0, kk, rq*4 + m);
            }
        }
        float bb = bias[j];
        #pragma unroll
        for (int m = 0; m < 4; ++m) op[(r0 + rq*4 + m) * H + j] = acc[m] + bb;
    }
    rg_barrier(mybar, ++gen);

    // ---- switch Ws to decoder Wh slice ----
    #pragma unroll
    for (int i = 0; i < 16; ++i) {
        int u = tid + i * 256;
        int k = u >> 3, f4 = u & 7;
        int gate = f4 >> 1, cc4 = (f4 & 1) * 4;
        *(float4*)&WsL[k*32 + f4*4] = *(const float4*)&dec_Wh[k*G4 + gate*512 + hc0 + cc4];
    }
    const float* mu_p = out + OUT_MU;
    const float* lv_p = out + OUT_LV;

    // ---- decoder (logits of step t-1's h fused into step t) ----
    #pragma unroll 1
    for (int t = 0; t < T; ++t) {
        float* ho = ((t + 1) & 1) ? hb1 : hb0;
        if (t == 0) {
            lstm_step_body<true>(tid, r0, hc0, cg, nullptr, nullptr, ho, cbuf,
                                 dec_proj, nullptr, mu_p, lv_p, eps,
                                 Wout, bout, out, -1, WsL, htf, gsf, lp);
        } else {
            const float* hi = (t & 1) ? hb1 : hb0;
            lstm_step_body<false>(tid, r0, hc0, cg, hi, cbuf, ho, cbuf,
                                  dec_proj, target + (t - 1) * B, nullptr, nullptr, nullptr,
                                  Wout, bout, out, t - 1, WsL, htf, gsf, lp);
        }
        rg_barrier(mybar, ++gen);
    }

    // ---- final logits: hs[255] = hA, row r0+cg ----
    {
        int v = tid & 31, ks = tid >> 5;
        float lacc = 0.f;
        if (v < V) {
            const float* hr = hA + (r0 + cg) * H + ks * 64;
            const float* wr = Wout + (ks * 64) * V + v;
            #pragma unroll 8
            for (int k = 0; k < 64; ++k) lacc += hr[k] * wr[k * V];
        }
        lp[tid] = lacc;
        __syncthreads();
        if (tid < 32) {
            int vv = tid;
            float sum = 0.f;
            #pragma unroll
            for (int ks2 = 0; ks2 < 8; ++ks2) sum += lp[ks2 * 32 + vv];
            float val = (vv < V) ? sum + bout[vv] : -INFINITY;
            float m = val;
            #pragma unroll
            for (int s = 16; s >= 1; s >>= 1) m = fmaxf(m, __shfl_xor(m, s, 32));
            float e = (vv < V) ? __expf(val - m) : 0.f;
            #pragma unroll
            for (int s = 16; s >= 1; s >>= 1) e += __shfl_xor(e, s, 32);
            float lse = m + __logf(e);
            if (vv < V) out[(255 * B + (r0 + cg)) * V + vv] = val - lse;
        }
    }
}

// ---------------------------------------------------------------------------
extern "C" void kernel_launch(void* const* d_in, const int* in_sizes, int n_in,
                              void* d_out, int out_size, void* d_ws, size_t ws_size,
                              hipStream_t stream)
{
    const int*   x         = (const int*)  d_in[0];
    const int*   target    = (const int*)  d_in[1];
    const float* hidden    = (const float*)d_in[2];
    const float* eps       = (const float*)d_in[3];
    const float* enc_embed = (const float*)d_in[4];
    const float* enc_Wi    = (const float*)d_in[5];
    const float* enc_Wh    = (const float*)d_in[6];
    const float* enc_b     = (const float*)d_in[7];
    const float* Wmu       = (const float*)d_in[8];
    const float* bmu       = (const float*)d_in[9];
    const float* Wlv       = (const float*)d_in[10];
    const float* blv       = (const float*)d_in[11];
    const float* dec_embed = (const float*)d_in[12];
    const float* dec_Wi    = (const float*)d_in[13];
    const float* dec_Wh    = (const float*)d_in[14];
    const float* dec_b     = (const float*)d_in[15];
    const float* Wout      = (const float*)d_in[16];
    const float* bout      = (const float*)d_in[17];
    float* out = (float*)d_out;
    float* ws  = (float*)d_ws;

    float* enc_proj = ws;                       // 28*2048
    float* dec_proj = enc_proj + V * G4;        // 28*2048
    float* hA       = dec_proj + V * G4;        // 256*512
    float* hB       = hA + B * H;
    float* cb       = hB + B * H;
    int*   bar      = (int*)(cb + B * H);       // 128 ints (4 ctrs, stride 32)

    proj_kernel<<<64, 256, 0, stream>>>(enc_embed, enc_Wi, enc_b,
                                        dec_embed, dec_Wi, dec_b,
                                        enc_proj, dec_proj, bar);
    vae_mega_kernel<<<256, 256, 0, stream>>>(x, target, hidden, eps,
                                             enc_Wh, dec_Wh,
                                             Wmu, bmu, Wlv, blv, Wout, bout,
                                             enc_proj, dec_proj,
                                             hA, hB, cb, bar, out);
}

// Round 4
// 6267.200 us; speedup vs baseline: 5.9496x; 5.9496x over previous
//
#include <hip/hip_runtime.h>
#include <math.h>

#define B 256
#define H 512
#define T 256
#define V 28
#define G4 2048  // 4*H

#define OUT_MU 1835008            // T*B*V
#define OUT_LV (1835008+131072)

typedef short short8 __attribute__((ext_vector_type(8)));
typedef float f32x4 __attribute__((ext_vector_type(4)));

__device__ __forceinline__ float fast_sigmoid(float x) {
    x = fminf(fmaxf(x, -30.f), 30.f);
    return 1.0f / (1.0f + __expf(-x));
}
__device__ __forceinline__ float fast_tanh(float x) {
    x = fminf(fmaxf(x, -15.f), 15.f);
    float e = __expf(2.0f * x);
    return (e - 1.0f) / (e + 1.0f);
}

// round-to-nearest-even f32 -> bf16 bits
__device__ __forceinline__ unsigned short bf16rn(float x) {
    unsigned int u = __float_as_uint(x);
    return (unsigned short)((u + 0x7FFFu + ((u >> 16) & 1u)) >> 16);
}
__device__ __forceinline__ void split2(float x, unsigned short& h, unsigned short& l) {
    h = bf16rn(x);
    float hf = __uint_as_float(((unsigned int)h) << 16);
    l = bf16rn(x - hf);
}

// ---------------------------------------------------------------------------
// K1: proj = embed @ Wi + b (enc mat0 / dec mat1), [28,512]@[512,2048]. Once.
// ---------------------------------------------------------------------------
__global__ __launch_bounds__(256) void proj_kernel(
    const float* __restrict__ enc_embed, const float* __restrict__ enc_Wi, const float* __restrict__ enc_b,
    const float* __restrict__ dec_embed, const float* __restrict__ dec_Wi, const float* __restrict__ dec_b,
    float* __restrict__ enc_proj, float* __restrict__ dec_proj)
{
    __shared__ float emb[V][513];
    int mat = blockIdx.x >> 5;
    int cg  = blockIdx.x & 31;
    int c0  = cg * 64;
    const float* embed = mat ? dec_embed : enc_embed;
    const float* Wi    = mat ? dec_Wi    : enc_Wi;
    const float* bias  = mat ? dec_b     : enc_b;
    float*       proj  = mat ? dec_proj  : enc_proj;
    int tid = threadIdx.x;
    #pragma unroll
    for (int i = 0; i < 14; ++i) {
        int u = tid + i * 256;
        int r = u >> 7, q = u & 127;
        float4 vv = *(const float4*)&embed[r * H + q * 4];
        emb[r][q*4+0] = vv.x; emb[r][q*4+1] = vv.y; emb[r][q*4+2] = vv.z; emb[r][q*4+3] = vv.w;
    }
    __syncthreads();
    int col = c0 + (tid & 63);
    int rg  = tid >> 6;
    float acc[7] = {0,0,0,0,0,0,0};
    for (int k = 0; k < H; ++k) {
        float w = Wi[k * G4 + col];
        #pragma unroll
        for (int r = 0; r < 7; ++r) acc[r] += w * emb[rg*7 + r][k];
    }
    float bb = bias[col];
    #pragma unroll
    for (int r = 0; r < 7; ++r) proj[(rg*7 + r) * G4 + col] = acc[r] + bb;
}

// ---------------------------------------------------------------------------
// K1b: transpose + split Wh (f32 [512][2048]) -> WT_hi/lo (bf16 [2048][512]).
// grid 512 = 2 mats x 8 kblk x 32 cblk, block 256.  Once, off critical path.
// ---------------------------------------------------------------------------
__global__ __launch_bounds__(256) void wsplit_kernel(
    const float* __restrict__ encW, const float* __restrict__ decW,
    unsigned short* __restrict__ WTeh, unsigned short* __restrict__ WTel,
    unsigned short* __restrict__ WTdh, unsigned short* __restrict__ WTdl)
{
    __shared__ float tile[64][65];
    int bid = blockIdx.x;
    int mat = bid >> 8;
    int kb  = (bid >> 5) & 7;
    int cb  = bid & 31;
    const float* W = mat ? decW : encW;
    unsigned short* Th = mat ? WTdh : WTeh;
    unsigned short* Tl = mat ? WTdl : WTel;
    int k0 = kb * 64, c0 = cb * 64;
    int tid = threadIdx.x;
    #pragma unroll
    for (int i = 0; i < 4; ++i) {
        int u = tid + i * 256;
        int kk = u >> 4, cq = u & 15;
        float4 vv = *(const float4*)&W[(k0 + kk) * G4 + c0 + cq * 4];
        tile[kk][cq*4+0] = vv.x; tile[kk][cq*4+1] = vv.y;
        tile[kk][cq*4+2] = vv.z; tile[kk][cq*4+3] = vv.w;
    }
    __syncthreads();
    #pragma unroll
    for (int i = 0; i < 4; ++i) {
        int u = tid + i * 256;
        int c = u >> 4, kq = u & 15;
        ushort4 hh, ll;
        float x0 = tile[kq*4+0][c], x1 = tile[kq*4+1][c];
        float x2 = tile[kq*4+2][c], x3 = tile[kq*4+3][c];
        split2(x0, hh.x, ll.x); split2(x1, hh.y, ll.y);
        split2(x2, hh.z, ll.z); split2(x3, hh.w, ll.w);
        size_t off = (size_t)(c0 + c) * 512 + k0 + kq * 4;
        *(ushort4*)&Th[off] = hh;
        *(ushort4*)&Tl[off] = ll;
    }
}

// ---------------------------------------------------------------------------
// K2: one LSTM step via split-bf16 MFMA.
//   g[256,2048] = h@Wh (3x mfma_16x16x32_bf16: hi*Whi + hi*Wlo + lo*Whi)
//   then gates -> h_out/c_out.  256 blocks x 512 thr (8 waves).
//   Block = 32 rows x 16 h-cols x 4 gates. Wave (rt,gate) = one 16x16 tile.
//   B frags: direct global->VGPR from WT (L2-resident, XCD-affine).
//   A frags: h rows staged once in LDS as bf16 hi/lo (+8 ushort row pad).
//   logit_t>=0: fused log_softmax of h_in row `bid` (prev step's h) -> out.
// ---------------------------------------------------------------------------
__global__ __launch_bounds__(512) void step_mfma(
    const float* __restrict__ proj,     // [V][2048], bias folded
    const int*   __restrict__ tok_idx,  // per-row token, nullptr -> SOS(0)
    const unsigned short* __restrict__ WTh,  // [2048][512] bf16 hi
    const unsigned short* __restrict__ WTl,  // [2048][512] bf16 lo
    const float* __restrict__ h_in, const float* __restrict__ c_in,
    float* __restrict__ h_out, float* __restrict__ c_out,
    const float* __restrict__ Wout, const float* __restrict__ bout,
    float* __restrict__ out, int logit_t)
{
    __shared__ unsigned short Ah[32 * 520];
    __shared__ unsigned short Al[32 * 520];
    __shared__ float gt[32 * 65];
    __shared__ float lp[512];

    int tid = threadIdx.x, bid = blockIdx.x;
    // XCD-affine col mapping: bid&7 = XCD -> h-col band [64*xcd, 64*xcd+64)
    int cg = ((bid & 7) << 2) | ((bid >> 3) & 3);   // 0..31  (16 h-cols)
    int rg = bid >> 5;                              // 0..7   (32 rows)
    int r0 = rg * 32, hc0 = cg * 16;

    // ---- fused logit partials: row = bid, strip ks of 32 k ----
    if (logit_t >= 0) {
        int v = tid & 31, ks = tid >> 5;
        float lacc = 0.f;
        if (v < V) {
            const float* hr = h_in + bid * H + ks * 32;
            const float* wr = Wout + (ks * 32) * V + v;
            #pragma unroll 8
            for (int k = 0; k < 32; ++k) lacc += hr[k] * wr[k * V];
        }
        lp[tid] = lacc;
    }

    // ---- stage A: 32 rows x 512 f32 -> bf16 hi/lo in LDS ----
    #pragma unroll
    for (int i = 0; i < 8; ++i) {
        int u = tid + i * 512;
        int row = u >> 7, q = u & 127;
        float4 vv = *(const float4*)&h_in[(r0 + row) * H + q * 4];
        ushort4 hh, ll;
        split2(vv.x, hh.x, ll.x); split2(vv.y, hh.y, ll.y);
        split2(vv.z, hh.z, ll.z); split2(vv.w, hh.w, ll.w);
        *(ushort4*)&Ah[row * 520 + q * 4] = hh;
        *(ushort4*)&Al[row * 520 + q * 4] = ll;
    }
    __syncthreads();

    // ---- MFMA k-loop: wave (rt, gate), tile 16 rows x 16 cols ----
    int wid = tid >> 6, lane = tid & 63;
    int rt = wid >> 2, gate = wid & 3;
    int lr = lane & 15, kg = lane >> 4;
    f32x4 acc_hh = {0.f, 0.f, 0.f, 0.f};
    f32x4 acc_hl = {0.f, 0.f, 0.f, 0.f};
    f32x4 acc_lh = {0.f, 0.f, 0.f, 0.f};
    const unsigned short* bhp = WTh + (size_t)(gate * 512 + hc0 + lr) * 512 + kg * 8;
    const unsigned short* blp = WTl + (size_t)(gate * 512 + hc0 + lr) * 512 + kg * 8;
    const unsigned short* ahp = &Ah[(rt * 16 + lr) * 520 + kg * 8];
    const unsigned short* alp = &Al[(rt * 16 + lr) * 520 + kg * 8];
    #pragma unroll
    for (int k0 = 0; k0 < 16; ++k0) {
        short8 ah = *(const short8*)(ahp + k0 * 32);
        short8 al = *(const short8*)(alp + k0 * 32);
        short8 bh = *(const short8*)(bhp + k0 * 32);
        short8 bl = *(const short8*)(blp + k0 * 32);
        acc_hh = __builtin_amdgcn_mfma_f32_16x16x32_bf16(ah, bh, acc_hh, 0, 0, 0);
        acc_hl = __builtin_amdgcn_mfma_f32_16x16x32_bf16(ah, bl, acc_hl, 0, 0, 0);
        acc_lh = __builtin_amdgcn_mfma_f32_16x16x32_bf16(al, bh, acc_lh, 0, 0, 0);
    }
    // C/D layout (m89-verified): col = lane&15, row = (lane>>4)*4 + reg
    #pragma unroll
    for (int r = 0; r < 4; ++r) {
        int row = rt * 16 + kg * 4 + r;
        gt[row * 65 + gate * 16 + lr] = acc_hh[r] + acc_hl[r] + acc_lh[r];
    }
    __syncthreads();

    // ---- gates epilogue: 1 output/thread ----
    {
        int row = tid >> 4, hcol = tid & 15;
        int gr = r0 + row, j = hc0 + hcol;
        int tok = tok_idx ? tok_idx[gr] : 0;
        const float* pr = proj + tok * G4;
        float gi = gt[row * 65 +      hcol] + pr[j];
        float gf = gt[row * 65 + 16 + hcol] + pr[512 + j];
        float gg = gt[row * 65 + 32 + hcol] + pr[1024 + j];
        float go = gt[row * 65 + 48 + hcol] + pr[1536 + j];
        float co = c_in[gr * H + j];
        float cn = fast_sigmoid(gf) * co + fast_sigmoid(gi) * fast_tanh(gg);
        float hn = fast_sigmoid(go) * fast_tanh(cn);
        c_out[gr * H + j] = cn;
        h_out[gr * H + j] = hn;
    }

    // ---- fused logit finish: lanes 0-31 of wave 0 ----
    if (logit_t >= 0 && tid < 32) {
        int v = tid;
        float sum = 0.f;
        #pragma unroll
        for (int ks = 0; ks < 16; ++ks) sum += lp[ks * 32 + v];
        float val = (v < V) ? sum + bout[v] : -INFINITY;
        float m = val;
        #pragma unroll
        for (int s = 16; s >= 1; s >>= 1) m = fmaxf(m, __shfl_xor(m, s, 32));
        float e = (v < V) ? __expf(val - m) : 0.f;
        #pragma unroll
        for (int s = 16; s >= 1; s >>= 1) e += __shfl_xor(e, s, 32);
        float lse = m + __logf(e);
        if (v < V) out[(logit_t * B + bid) * V + v] = val - lse;
    }
}

// ---------------------------------------------------------------------------
// K4: standalone logits for the final hidden state (t = 255). grid 32 x 256.
// ---------------------------------------------------------------------------
__global__ __launch_bounds__(256) void logits_tail(
    const float* __restrict__ h, const float* __restrict__ Wout,
    const float* __restrict__ bout, float* __restrict__ out)
{
    int tid  = threadIdx.x;
    int wid  = tid >> 6;
    int lane = tid & 63;
    int half = lane >> 5;
    int v    = lane & 31;
    int row  = blockIdx.x * 8 + wid * 2 + half;
    float a0 = 0.f, a1 = 0.f, a2 = 0.f, a3 = 0.f;
    if (v < V) {
        const float* hr = h + row * H;
        #pragma unroll 4
        for (int k = 0; k < H; k += 4) {
            a0 += hr[k+0] * Wout[(k+0)*V + v];
            a1 += hr[k+1] * Wout[(k+1)*V + v];
            a2 += hr[k+2] * Wout[(k+2)*V + v];
            a3 += hr[k+3] * Wout[(k+3)*V + v];
        }
    }
    float val = (v < V) ? ((a0+a1) + (a2+a3) + bout[v]) : -INFINITY;
    float m = val;
    #pragma unroll
    for (int s = 16; s >= 1; s >>= 1) m = fmaxf(m, __shfl_xor(m, s, 32));
    float e = (v < V) ? __expf(val - m) : 0.f;
    #pragma unroll
    for (int s = 16; s >= 1; s >>= 1) e += __shfl_xor(e, s, 32);
    float lse = m + __logf(e);
    if (v < V) out[(255 * B + row) * V + v] = val - lse;
}

// ---------------------------------------------------------------------------
// K3: mu/logvar = h @ Wmu/Wlv + b -> d_out.  grid 64.
// ---------------------------------------------------------------------------
__global__ __launch_bounds__(256) void latent_kernel(
    const float* __restrict__ h,
    const float* __restrict__ Wmu, const float* __restrict__ bmu,
    const float* __restrict__ Wlv, const float* __restrict__ blv,
    float* __restrict__ dout)
{
    __shared__ float Ht[64][68];
    __shared__ float Ww[64][64];
    int bid = blockIdx.x;
    int mat = bid & 1;
    int cg  = (bid >> 1) & 7;
    int rg  = bid >> 4;
    int r0 = rg * 64, c0 = cg * 64;
    const float* W    = mat ? Wlv : Wmu;
    const float* bias = mat ? blv : bmu;
    float* outp = dout + (mat ? OUT_LV : OUT_MU);
    int tid = threadIdx.x;
    int tx = tid & 15, ty = tid >> 4;
    float acc[4][4] = {};
    for (int k0 = 0; k0 < H; k0 += 64) {
        #pragma unroll
        for (int i = 0; i < 4; ++i) {
            int u = tid + i * 256;
            int rrow = u >> 4, kq = u & 15;
            float4 vv = *(const float4*)&h[(r0 + rrow) * H + k0 + kq * 4];
            Ht[kq*4+0][rrow] = vv.x; Ht[kq*4+1][rrow] = vv.y;
            Ht[kq*4+2][rrow] = vv.z; Ht[kq*4+3][rrow] = vv.w;
        }
        #pragma unroll
        for (int i = 0; i < 4; ++i) {
            int u = tid + i * 256;
            int kk = u >> 4, f4 = u & 15;
            *(float4*)&Ww[kk][f4 * 4] = *(const float4*)&W[(k0 + kk) * H + c0 + f4 * 4];
        }
        __syncthreads();
        #pragma unroll
        for (int kk = 0; kk < 64; ++kk) {
            float4 a4 = *(const float4*)&Ht[kk][ty * 4];
            float4 b4 = *(const float4*)&Ww[kk][tx * 4];
            acc[0][0] += a4.x*b4.x; acc[0][1] += a4.x*b4.y; acc[0][2] += a4.x*b4.z; acc[0][3] += a4.x*b4.w;
            acc[1][0] += a4.y*b4.x; acc[1][1] += a4.y*b4.y; acc[1][2] += a4.y*b4.z; acc[1][3] += a4.y*b4.w;
            acc[2][0] += a4.z*b4.x; acc[2][1] += a4.z*b4.y; acc[2][2] += a4.z*b4.z; acc[2][3] += a4.z*b4.w;
            acc[3][0] += a4.w*b4.x; acc[3][1] += a4.w*b4.y; acc[3][2] += a4.w*b4.z; acc[3][3] += a4.w*b4.w;
        }
        __syncthreads();
    }
    #pragma unroll
    for (int i = 0; i < 4; ++i) {
        float4 st;
        st.x = acc[i][0] + bias[c0 + tx*4 + 0];
        st.y = acc[i][1] + bias[c0 + tx*4 + 1];
        st.z = acc[i][2] + bias[c0 + tx*4 + 2];
        st.w = acc[i][3] + bias[c0 + tx*4 + 3];
        *(float4*)&outp[(r0 + ty*4 + i) * H + c0 + tx*4] = st;
    }
}

// K3b: z = mu + eps * exp(0.5*logvar)
__global__ void z_kernel(const float* __restrict__ dout, const float* __restrict__ eps,
                         float* __restrict__ z)
{
    int i = blockIdx.x * 256 + threadIdx.x;
    float mu = dout[OUT_MU + i];
    float lv = dout[OUT_LV + i];
    z[i] = mu + eps[i] * __expf(0.5f * lv);
}

// ---------------------------------------------------------------------------
extern "C" void kernel_launch(void* const* d_in, const int* in_sizes, int n_in,
                              void* d_out, int out_size, void* d_ws, size_t ws_size,
                              hipStream_t stream)
{
    const int*   x         = (const int*)  d_in[0];
    const int*   target    = (const int*)  d_in[1];
    const float* hidden    = (const float*)d_in[2];
    const float* eps       = (const float*)d_in[3];
    const float* enc_embed = (const float*)d_in[4];
    const float* enc_Wi    = (const float*)d_in[5];
    const float* enc_Wh    = (const float*)d_in[6];
    const float* enc_b     = (const float*)d_in[7];
    const float* Wmu       = (const float*)d_in[8];
    const float* bmu       = (const float*)d_in[9];
    const float* Wlv       = (const float*)d_in[10];
    const float* blv       = (const float*)d_in[11];
    const float* dec_embed = (const float*)d_in[12];
    const float* dec_Wi    = (const float*)d_in[13];
    const float* dec_Wh    = (const float*)d_in[14];
    const float* dec_b     = (const float*)d_in[15];
    const float* Wout      = (const float*)d_in[16];
    const float* bout      = (const float*)d_in[17];
    float* out = (float*)d_out;
    float* ws  = (float*)d_ws;

    float* enc_proj = ws;                          // 28*2048 f32
    float* dec_proj = enc_proj + V * G4;
    float* hA       = dec_proj + V * G4;           // 256*512 f32
    float* hB       = hA + B * H;
    float* cb       = hB + B * H;
    float* zb       = cb + B * H;
    unsigned short* WTeh = (unsigned short*)(zb + B * H);  // 2048*512 bf16 each
    unsigned short* WTel = WTeh + 2048 * 512;
    unsigned short* WTdh = WTel + 2048 * 512;
    unsigned short* WTdl = WTdh + 2048 * 512;      // total ~10.9 MB

    proj_kernel<<<64, 256, 0, stream>>>(enc_embed, enc_Wi, enc_b,
                                        dec_embed, dec_Wi, dec_b,
                                        enc_proj, dec_proj);
    wsplit_kernel<<<512, 256, 0, stream>>>(enc_Wh, dec_Wh, WTeh, WTel, WTdh, WTdl);

    // ---- encoder ----
    for (int t = 0; t < T; ++t) {
        const float* hi = (t == 0) ? hidden : ((t & 1) ? hB : hA);
        const float* ci = (t == 0) ? hidden : cb;
        float* ho = ((t + 1) & 1) ? hB : hA;
        step_mfma<<<256, 512, 0, stream>>>(enc_proj, x + t * B, WTeh, WTel,
                                           hi, ci, ho, cb,
                                           nullptr, nullptr, nullptr, -1);
    }
    // final encoder h = hA
    latent_kernel<<<64, 256, 0, stream>>>(hA, Wmu, bmu, Wlv, blv, out);
    z_kernel<<<512, 256, 0, stream>>>(out, eps, zb);

    // ---- decoder: logits of step t-1's h fused into launch t ----
    for (int t = 0; t < T; ++t) {
        const float* hi = (t == 0) ? zb : ((t & 1) ? hB : hA);
        const float* ci = (t == 0) ? zb : cb;
        float* ho = ((t + 1) & 1) ? hB : hA;
        const int* tok = (t == 0) ? nullptr : (target + (t - 1) * B);
        step_mfma<<<256, 512, 0, stream>>>(dec_proj, tok, WTdh, WTdl,
                                           hi, ci, ho, cb,
                                           Wout, bout, out, t - 1);
    }
    // logits for the last hidden state (hA after t=255)
    logits_tail<<<32, 256, 0, stream>>>(hA, Wout, bout, out);
}